// Round 9
// baseline (132.793 us; speedup 1.0000x reference)
//
#include <hip/hip_runtime.h>

// SparseMoE: T=4096, D=1024, E=8, H=2048, top_k=2.
// R9: R8 GEMM (128x128, BK=64 single-buf, swizzled global_load_lds, bf16
// partial-store epilogue — no atomics) + two occupancy/locality levers:
//   (1) __launch_bounds__(256,4): 4 blocks/CU (was 2) to TLP-hide the
//       per-K-step vmcnt(0) drain (m97 mechanism).
//   (2) bijective XCD-chunked swizzle: each XCD gets 512 consecutive tiles
//       = one expert -> its 4MB B panel fits the per-XCD 4MB L2.

#define NTOK 4096
#define DIM  1024
#define NEXP 8
#define HID  2048

#define BM 128
#define BN 128
#define BK 64

using u16    = unsigned short;
using u16x4  = __attribute__((ext_vector_type(4))) unsigned short;
using u16x8  = __attribute__((ext_vector_type(8))) unsigned short;
using bf16x8 = __attribute__((ext_vector_type(8))) __bf16;
using f32x4  = __attribute__((ext_vector_type(4))) float;

typedef const __attribute__((address_space(1))) unsigned char* gas1p;
typedef __attribute__((address_space(3))) unsigned char* gas3p;

__device__ __forceinline__ void gload16(void* lds, const void* g) {
  __builtin_amdgcn_global_load_lds((gas1p)g, (gas3p)lds, 16, 0, 0);
}

__device__ inline u16 f2bf(float f) {
  union { float f; unsigned u; } v; v.f = f;
  unsigned r = v.u + 0x7fffu + ((v.u >> 16) & 1u);  // RNE, no NaN in this data
  return (u16)(r >> 16);
}
__device__ inline float bf2f(u16 b) {
  union { unsigned u; float f; } v; v.u = ((unsigned)b) << 16; return v.f;
}

// ---------------- fp32 -> bf16 bulk convert (8 elems/thread) -----------------
__global__ __launch_bounds__(256) void convert_bf16(
    const float* __restrict__ in, u16* __restrict__ out) {
  int i = blockIdx.x * 256 + threadIdx.x;
  const float4* p = (const float4*)in + (size_t)i * 2;
  float4 a = p[0], b = p[1];
  u16x8 r;
  r[0] = f2bf(a.x); r[1] = f2bf(a.y); r[2] = f2bf(a.z); r[3] = f2bf(a.w);
  r[4] = f2bf(b.x); r[5] = f2bf(b.y); r[6] = f2bf(b.z); r[7] = f2bf(b.w);
  *((u16x8*)out + i) = r;
}

// -------- gating: fp64 logits, softmax, top-2 -> ws; also emits xbf ----------
__global__ __launch_bounds__(256) void gate_kernel(
    const float* __restrict__ x, const float* __restrict__ gW,
    const float* __restrict__ gb, float* __restrict__ probs,
    int* __restrict__ top2, u16* __restrict__ xbf) {
  const int wave = threadIdx.x >> 6;
  const int lane = threadIdx.x & 63;
  const int t = blockIdx.x * 4 + wave;

  const float4* xrow = (const float4*)(x + (size_t)t * DIM);
  double acc[NEXP];
#pragma unroll
  for (int e = 0; e < NEXP; ++e) acc[e] = 0.0;

#pragma unroll
  for (int c = 0; c < 4; ++c) {
    int idx = c * 64 + lane;          // float4 index; elems 4*idx..4*idx+3
    float4 xv = xrow[idx];
    u16x4 bv;
    bv[0] = f2bf(xv.x); bv[1] = f2bf(xv.y); bv[2] = f2bf(xv.z); bv[3] = f2bf(xv.w);
    *(u16x4*)(xbf + (size_t)t * DIM + 4 * idx) = bv;   // fused convert_x
#pragma unroll
    for (int e = 0; e < NEXP; ++e) {
      float4 wv = ((const float4*)(gW + (size_t)e * DIM))[idx];
      acc[e] += (double)xv.x * wv.x + (double)xv.y * wv.y +
                (double)xv.z * wv.z + (double)xv.w * wv.w;
    }
  }
#pragma unroll
  for (int e = 0; e < NEXP; ++e) {
    double v = acc[e];
#pragma unroll
    for (int off = 32; off > 0; off >>= 1) v += __shfl_down(v, off);
    acc[e] = v;
  }

  if (lane == 0) {
    double logits[NEXP];
#pragma unroll
    for (int e = 0; e < NEXP; ++e) logits[e] = acc[e] + (double)gb[e];
    double m = logits[0];
#pragma unroll
    for (int e = 1; e < NEXP; ++e) m = fmax(m, logits[e]);
    double p[NEXP], s = 0.0;
#pragma unroll
    for (int e = 0; e < NEXP; ++e) { p[e] = exp(logits[e] - m); s += p[e]; }
#pragma unroll
    for (int e = 0; e < NEXP; ++e) p[e] /= s;

    int i1 = 0;
#pragma unroll
    for (int e = 1; e < NEXP; ++e) if (p[e] > p[i1]) i1 = e;
    int i2 = (i1 == 0) ? 1 : 0;
#pragma unroll
    for (int e = 0; e < NEXP; ++e) {
      if (e != i1 && p[e] > p[i2]) i2 = e;
    }

#pragma unroll
    for (int e = 0; e < NEXP; ++e) probs[(size_t)t * NEXP + e] = (float)p[e];
    top2[t] = i1 | (i2 << 4);
  }
}

// ------- route: per-expert stable compaction (ballot prefix) + fp64 variance -
__global__ __launch_bounds__(256) void route_kernel(
    const float* __restrict__ probs, const int* __restrict__ top2,
    int* __restrict__ counts, int* __restrict__ lists,
    float* __restrict__ var_out) {
  const int e = blockIdx.x;
  const int tid = threadIdx.x;
  const int lane = tid & 63;
  const int wave = tid >> 6;

  __shared__ int wsum[4];
  __shared__ double ds[4], dq[4];

  double s = 0.0, q = 0.0;
  int base = 0;

  for (int c = 0; c < NTOK / 256; ++c) {
    int t = c * 256 + tid;
    float p = probs[(size_t)t * NEXP + e];
    s += (double)p;
    q += (double)p * (double)p;

    int m = top2[t];
    bool f = ((m & 15) == e) || (((m >> 4) & 15) == e);
    unsigned long long bal = __ballot(f);
    int before = __popcll(bal & ((1ull << lane) - 1ull));
    if (lane == 0) wsum[wave] = __popcll(bal);
    __syncthreads();
    int woff = 0;
#pragma unroll
    for (int w = 0; w < 4; ++w) if (w < wave) woff += wsum[w];
    int ctotal = wsum[0] + wsum[1] + wsum[2] + wsum[3];
    if (f) lists[e * NTOK + base + woff + before] = t;
    base += ctotal;
    __syncthreads();
  }
  if (tid == 0) counts[e] = base;

#pragma unroll
  for (int off = 32; off > 0; off >>= 1) {
    s += __shfl_down(s, off);
    q += __shfl_down(q, off);
  }
  if (lane == 0) { ds[wave] = s; dq[wave] = q; }
  __syncthreads();
  if (tid == 0) {
    double S = ds[0] + ds[1] + ds[2] + ds[3];
    double Q = dq[0] + dq[1] + dq[2] + dq[3];
    var_out[e] = (float)((Q - S * S / (double)NTOK) / (double)(NTOK - 1));
  }
}

// --------- gathered expert GEMM: R8 structure + occupancy/XCD levers ---------
// LDS tile (A and B): logical [128 rows][64 cols] bf16 row-major, 16B-chunk
// swizzle stored_c16 = c16 ^ (row&7). global_load_lds writes LDS linearly;
// global source carries the inverse (same) XOR. Epilogue: plain bf16 stores
// to partial[k][token][h], k = slot of expert e in token's top2.
__global__ __launch_bounds__(256, 4) void expert_gemm(
    const u16* __restrict__ xbf, const u16* __restrict__ wbf,
    const float* __restrict__ eb, const int* __restrict__ counts,
    const int* __restrict__ lists, const int* __restrict__ top2,
    u16* __restrict__ pbf) {
  __shared__ u16 As[BM * BK];   // 16 KB
  __shared__ u16 Bs[BN * BK];   // 16 KB
  __shared__ int tok[BM];
  __shared__ int kslot[BM];

  // bijective XCD-chunked swizzle (gridDim.x = 4096, 4096 % 8 == 0):
  // hw block i runs on XCD i%8; give XCD k the contiguous tile range
  // [k*512, (k+1)*512) = exactly one expert -> B panel (4MB) fits its L2.
  const int bid = (blockIdx.x & 7) * (4096 / 8) + (blockIdx.x >> 3);

  const int e  = bid >> 9;          // 512 tiles/expert: 32 rb x 16 cb
  const int rb = (bid >> 4) & 31;
  const int cb = bid & 15;
  const int cnt = counts[e];
  if (rb * BM >= cnt) return;

  const int tid  = threadIdx.x;
  const int wave = tid >> 6;
  const int lane = tid & 63;

  if (tid < BM) {
    int gi = rb * BM + tid;
    int tr = (gi < cnt) ? lists[e * NTOK + gi] : -1;
    tok[tid] = tr;
    kslot[tid] = (tr >= 0 && (top2[tr] & 15) == e) ? 0 : 1;
  }
  __syncthreads();

  // ---- staging precompute: 4 A-issues + 4 B-issues of 16B per thread ----
  const u16* asrc[4];
  const u16* bsrc[4];
  int ldsoff[4];
#pragma unroll
  for (int j = 0; j < 4; ++j) {
    const int idx  = (j * 4 + wave) * 64 + lane;  // 16B-chunk index in [0,1024)
    const int row  = idx >> 3;
    const int c16  = (idx & 7) ^ (row & 7);       // inverse swizzle on source
    int tr = tok[row]; if (tr < 0) tr = 0;        // clamped; row discarded later
    asrc[j] = xbf + (size_t)tr * DIM + c16 * 8;
    bsrc[j] = wbf + ((size_t)e * HID + (size_t)cb * BN + row) * DIM + c16 * 8;
    ldsoff[j] = (j * 4 + wave) * 512;             // wave-uniform base
  }

  const int wm = (wave >> 1) * 64;
  const int wn = (wave & 1) * 64;
  const int lr = lane & 15;
  const int hk = lane >> 4;        // k-group 0..3

  f32x4 acc[4][4];
#pragma unroll
  for (int m = 0; m < 4; ++m)
#pragma unroll
    for (int n = 0; n < 4; ++n) acc[m][n] = (f32x4)(0.0f);

  for (int k0 = 0; k0 < DIM; k0 += BK) {
#pragma unroll
    for (int j = 0; j < 4; ++j) gload16(&As[ldsoff[j]], asrc[j] + k0);
#pragma unroll
    for (int j = 0; j < 4; ++j) gload16(&Bs[ldsoff[j]], bsrc[j] + k0);

    __syncthreads();   // vmcnt(0) drain + barrier

    bf16x8 fa[2][4], fb[2][4];
#pragma unroll
    for (int kk = 0; kk < 2; ++kk) {
#pragma unroll
      for (int m = 0; m < 4; ++m) {
        const int row = wm + m * 16 + lr;
        const int c16 = (kk * 4 + hk) ^ (row & 7);
        fa[kk][m] = *(const bf16x8*)&As[row * 64 + c16 * 8];
      }
#pragma unroll
      for (int n = 0; n < 4; ++n) {
        const int row = wn + n * 16 + lr;
        const int c16 = (kk * 4 + hk) ^ (row & 7);
        fb[kk][n] = *(const bf16x8*)&Bs[row * 64 + c16 * 8];
      }
    }

#pragma unroll
    for (int kk = 0; kk < 2; ++kk)
#pragma unroll
      for (int m = 0; m < 4; ++m)
#pragma unroll
        for (int n = 0; n < 4; ++n)
          acc[m][n] = __builtin_amdgcn_mfma_f32_16x16x32_bf16(
              fa[kk][m], fb[kk][n], acc[m][n], 0, 0, 0);

    __syncthreads();
  }

  // ---- epilogue: plain bf16 partial stores (deterministic, no atomics) ----
#pragma unroll
  for (int n = 0; n < 4; ++n) {
    const int hcol = cb * BN + wn + n * 16 + lr;
#pragma unroll
    for (int m = 0; m < 4; ++m) {
#pragma unroll
      for (int i = 0; i < 4; ++i) {
        int rloc = wm + m * 16 + hk * 4 + i;   // C/D: row=(lane>>4)*4+i
        int tr = tok[rloc];
        if (tr >= 0)
          pbf[((size_t)kslot[rloc] * NTOK + tr) * HID + hcol] =
              f2bf(acc[m][n][i]);
      }
    }
  }
}

// ---- combine: out[t] = 0.5*(p0 + p1 + b_e1 + b_e2); fully memory-bound -----
__global__ __launch_bounds__(256) void combine_kernel(
    const u16* __restrict__ pbf, const int* __restrict__ top2,
    const float* __restrict__ eb, float* __restrict__ out) {
  const int t = blockIdx.x;
  const int h = threadIdx.x * 8;
  const int m2 = top2[t];
  const int e1 = m2 & 15, e2 = (m2 >> 4) & 15;

  u16x8 p0 = *(const u16x8*)&pbf[(size_t)t * HID + h];
  u16x8 p1 = *(const u16x8*)&pbf[((size_t)NTOK + t) * HID + h];
  const float4* b1 = (const float4*)&eb[e1 * HID + h];
  const float4* b2 = (const float4*)&eb[e2 * HID + h];
  float4 b1a = b1[0], b1b = b1[1], b2a = b2[0], b2b = b2[1];

  float4 o0, o1;
  o0.x = 0.5f * (bf2f(p0[0]) + bf2f(p1[0]) + b1a.x + b2a.x);
  o0.y = 0.5f * (bf2f(p0[1]) + bf2f(p1[1]) + b1a.y + b2a.y);
  o0.z = 0.5f * (bf2f(p0[2]) + bf2f(p1[2]) + b1a.z + b2a.z);
  o0.w = 0.5f * (bf2f(p0[3]) + bf2f(p1[3]) + b1a.w + b2a.w);
  o1.x = 0.5f * (bf2f(p0[4]) + bf2f(p1[4]) + b1b.x + b2b.x);
  o1.y = 0.5f * (bf2f(p0[5]) + bf2f(p1[5]) + b1b.y + b2b.y);
  o1.z = 0.5f * (bf2f(p0[6]) + bf2f(p1[6]) + b1b.z + b2b.z);
  o1.w = 0.5f * (bf2f(p0[7]) + bf2f(p1[7]) + b1b.w + b2b.w);

  float4* po = (float4*)&out[(size_t)t * HID + h];
  po[0] = o0; po[1] = o1;
}

extern "C" void kernel_launch(void* const* d_in, const int* in_sizes, int n_in,
                              void* d_out, int out_size, void* d_ws, size_t ws_size,
                              hipStream_t stream) {
  const float* x  = (const float*)d_in[0];   // [4096,1024]
  const float* gW = (const float*)d_in[1];   // [8,1024]
  const float* gb = (const float*)d_in[2];   // [8]
  const float* eW = (const float*)d_in[3];   // [8,2048,1024]
  const float* eb = (const float*)d_in[4];   // [8,2048]

  float* out = (float*)d_out;
  float* var_out = out + (size_t)NTOK * HID;

  // ws layout
  char* ws = (char*)d_ws;
  int*   counts = (int*)ws;                                   // 32 B
  int*   lists  = (int*)(ws + 1024);                          // 128 KB
  float* probs  = (float*)(ws + 1024 + 131072);               // 128 KB
  int*   top2   = (int*)(ws + 1024 + 2 * 131072);             // 16 KB
  u16*   xbf    = (u16*)(ws + 294912);                        // 8 MB
  u16*   wbf    = (u16*)((char*)xbf + (size_t)NTOK * DIM * 2);// 32 MB
  u16*   pbf    = (u16*)((char*)wbf + (size_t)NEXP * HID * DIM * 2);  // 32 MB

  convert_bf16<<<(NEXP * HID * DIM) / (256 * 8), 256, 0, stream>>>(eW, wbf);
  gate_kernel<<<NTOK / 4, 256, 0, stream>>>(x, gW, gb, probs, top2, xbf);
  route_kernel<<<NEXP, 256, 0, stream>>>(probs, top2, counts, lists, var_out);
  expert_gemm<<<NEXP * (NTOK / BM) * (HID / BN), 256, 0, stream>>>(
      xbf, wbf, eb, counts, lists, top2, pbf);
  combine_kernel<<<NTOK, 256, 0, stream>>>(pbf, top2, eb, out);
}

// Round 10
// 117.832 us; speedup vs baseline: 1.1270x; 1.1270x over previous
//
#include <hip/hip_runtime.h>

// SparseMoE: T=4096, D=1024, E=8, H=2048, top_k=2.
// R10: R8 base (128x128, swizzled global_load_lds, bf16 partial epilogue,
// no atomics, no XCD swizzle, launch_bounds(256,2)) + ONE change: counted-
// vmcnt double-buffer K-loop (T4/AITER pattern). Raw s_barrier (no compiler
// vmcnt(0) drain); steady-state waits vmcnt(8) so the next tile's 8
// global_load_lds stay in flight across the barrier; last iter peels to
// vmcnt(0). LDS 64KB -> 2 blocks/CU (same as R8's measured occupancy).

#define NTOK 4096
#define DIM  1024
#define NEXP 8
#define HID  2048

#define BM 128
#define BN 128
#define BK 64
#define NT (DIM / BK)   // 16 K-tiles

using u16    = unsigned short;
using u16x4  = __attribute__((ext_vector_type(4))) unsigned short;
using u16x8  = __attribute__((ext_vector_type(8))) unsigned short;
using bf16x8 = __attribute__((ext_vector_type(8))) __bf16;
using f32x4  = __attribute__((ext_vector_type(4))) float;

typedef const __attribute__((address_space(1))) unsigned char* gas1p;
typedef __attribute__((address_space(3))) unsigned char* gas3p;

__device__ __forceinline__ void gload16(void* lds, const void* g) {
  __builtin_amdgcn_global_load_lds((gas1p)g, (gas3p)lds, 16, 0, 0);
}

__device__ inline u16 f2bf(float f) {
  union { float f; unsigned u; } v; v.f = f;
  unsigned r = v.u + 0x7fffu + ((v.u >> 16) & 1u);  // RNE, no NaN in this data
  return (u16)(r >> 16);
}
__device__ inline float bf2f(u16 b) {
  union { unsigned u; float f; } v; v.u = ((unsigned)b) << 16; return v.f;
}

// ---------------- fp32 -> bf16 bulk convert (8 elems/thread) -----------------
__global__ __launch_bounds__(256) void convert_bf16(
    const float* __restrict__ in, u16* __restrict__ out) {
  int i = blockIdx.x * 256 + threadIdx.x;
  const float4* p = (const float4*)in + (size_t)i * 2;
  float4 a = p[0], b = p[1];
  u16x8 r;
  r[0] = f2bf(a.x); r[1] = f2bf(a.y); r[2] = f2bf(a.z); r[3] = f2bf(a.w);
  r[4] = f2bf(b.x); r[5] = f2bf(b.y); r[6] = f2bf(b.z); r[7] = f2bf(b.w);
  *((u16x8*)out + i) = r;
}

// -------- gating: fp64 logits, softmax, top-2 -> ws; also emits xbf ----------
__global__ __launch_bounds__(256) void gate_kernel(
    const float* __restrict__ x, const float* __restrict__ gW,
    const float* __restrict__ gb, float* __restrict__ probs,
    int* __restrict__ top2, u16* __restrict__ xbf) {
  const int wave = threadIdx.x >> 6;
  const int lane = threadIdx.x & 63;
  const int t = blockIdx.x * 4 + wave;

  const float4* xrow = (const float4*)(x + (size_t)t * DIM);
  double acc[NEXP];
#pragma unroll
  for (int e = 0; e < NEXP; ++e) acc[e] = 0.0;

#pragma unroll
  for (int c = 0; c < 4; ++c) {
    int idx = c * 64 + lane;          // float4 index; elems 4*idx..4*idx+3
    float4 xv = xrow[idx];
    u16x4 bv;
    bv[0] = f2bf(xv.x); bv[1] = f2bf(xv.y); bv[2] = f2bf(xv.z); bv[3] = f2bf(xv.w);
    *(u16x4*)(xbf + (size_t)t * DIM + 4 * idx) = bv;   // fused convert_x
#pragma unroll
    for (int e = 0; e < NEXP; ++e) {
      float4 wv = ((const float4*)(gW + (size_t)e * DIM))[idx];
      acc[e] += (double)xv.x * wv.x + (double)xv.y * wv.y +
                (double)xv.z * wv.z + (double)xv.w * wv.w;
    }
  }
#pragma unroll
  for (int e = 0; e < NEXP; ++e) {
    double v = acc[e];
#pragma unroll
    for (int off = 32; off > 0; off >>= 1) v += __shfl_down(v, off);
    acc[e] = v;
  }

  if (lane == 0) {
    double logits[NEXP];
#pragma unroll
    for (int e = 0; e < NEXP; ++e) logits[e] = acc[e] + (double)gb[e];
    double m = logits[0];
#pragma unroll
    for (int e = 1; e < NEXP; ++e) m = fmax(m, logits[e]);
    double p[NEXP], s = 0.0;
#pragma unroll
    for (int e = 0; e < NEXP; ++e) { p[e] = exp(logits[e] - m); s += p[e]; }
#pragma unroll
    for (int e = 0; e < NEXP; ++e) p[e] /= s;

    int i1 = 0;
#pragma unroll
    for (int e = 1; e < NEXP; ++e) if (p[e] > p[i1]) i1 = e;
    int i2 = (i1 == 0) ? 1 : 0;
#pragma unroll
    for (int e = 0; e < NEXP; ++e) {
      if (e != i1 && p[e] > p[i2]) i2 = e;
    }

#pragma unroll
    for (int e = 0; e < NEXP; ++e) probs[(size_t)t * NEXP + e] = (float)p[e];
    top2[t] = i1 | (i2 << 4);
  }
}

// ------- route: per-expert stable compaction (ballot prefix) + fp64 variance -
__global__ __launch_bounds__(256) void route_kernel(
    const float* __restrict__ probs, const int* __restrict__ top2,
    int* __restrict__ counts, int* __restrict__ lists,
    float* __restrict__ var_out) {
  const int e = blockIdx.x;
  const int tid = threadIdx.x;
  const int lane = tid & 63;
  const int wave = tid >> 6;

  __shared__ int wsum[4];
  __shared__ double ds[4], dq[4];

  double s = 0.0, q = 0.0;
  int base = 0;

  for (int c = 0; c < NTOK / 256; ++c) {
    int t = c * 256 + tid;
    float p = probs[(size_t)t * NEXP + e];
    s += (double)p;
    q += (double)p * (double)p;

    int m = top2[t];
    bool f = ((m & 15) == e) || (((m >> 4) & 15) == e);
    unsigned long long bal = __ballot(f);
    int before = __popcll(bal & ((1ull << lane) - 1ull));
    if (lane == 0) wsum[wave] = __popcll(bal);
    __syncthreads();
    int woff = 0;
#pragma unroll
    for (int w = 0; w < 4; ++w) if (w < wave) woff += wsum[w];
    int ctotal = wsum[0] + wsum[1] + wsum[2] + wsum[3];
    if (f) lists[e * NTOK + base + woff + before] = t;
    base += ctotal;
    __syncthreads();
  }
  if (tid == 0) counts[e] = base;

#pragma unroll
  for (int off = 32; off > 0; off >>= 1) {
    s += __shfl_down(s, off);
    q += __shfl_down(q, off);
  }
  if (lane == 0) { ds[wave] = s; dq[wave] = q; }
  __syncthreads();
  if (tid == 0) {
    double S = ds[0] + ds[1] + ds[2] + ds[3];
    double Q = dq[0] + dq[1] + dq[2] + dq[3];
    var_out[e] = (float)((Q - S * S / (double)NTOK) / (double)(NTOK - 1));
  }
}

// ---- gathered expert GEMM: counted-vmcnt dbuf (T4), swizzled, no atomics ----
// LDS per buffer: [128 rows][64 cols] bf16, 16B-chunk swizzle
// stored_c16 = c16 ^ (row&7). Steady-state K-loop never drains vmcnt to 0:
// vmcnt(8) = own next-tile loads may remain in flight; raw s_barrier makes
// the per-wave wait collective (all waves' cur-tile loads landed).
__global__ __launch_bounds__(256, 2) void expert_gemm(
    const u16* __restrict__ xbf, const u16* __restrict__ wbf,
    const int* __restrict__ counts, const int* __restrict__ lists,
    const int* __restrict__ top2, u16* __restrict__ pbf) {
  __shared__ u16 As[2][BM * BK];   // 2 x 16 KB
  __shared__ u16 Bs[2][BN * BK];   // 2 x 16 KB
  __shared__ int tok[BM];
  __shared__ int kslot[BM];

  const int bid = blockIdx.x;
  const int e  = bid >> 9;          // 512 tiles/expert: 32 rb x 16 cb
  const int rb = (bid >> 4) & 31;
  const int cb = bid & 15;
  const int cnt = counts[e];
  if (rb * BM >= cnt) return;

  const int tid  = threadIdx.x;
  const int wave = tid >> 6;
  const int lane = tid & 63;

  if (tid < BM) {
    int gi = rb * BM + tid;
    int tr = (gi < cnt) ? lists[e * NTOK + gi] : -1;
    tok[tid] = tr;
    kslot[tid] = (tr >= 0 && (top2[tr] & 15) == e) ? 0 : 1;
  }
  __syncthreads();

  // ---- staging precompute: 4 A-issues + 4 B-issues of 16B per thread ----
  const u16* asrc[4];
  const u16* bsrc[4];
  int ldsoff[4];
#pragma unroll
  for (int j = 0; j < 4; ++j) {
    const int idx  = (j * 4 + wave) * 64 + lane;  // 16B-chunk index in [0,1024)
    const int row  = idx >> 3;
    const int c16  = (idx & 7) ^ (row & 7);       // inverse swizzle on source
    int tr = tok[row]; if (tr < 0) tr = 0;        // clamped; row discarded later
    asrc[j] = xbf + (size_t)tr * DIM + c16 * 8;
    bsrc[j] = wbf + ((size_t)e * HID + (size_t)cb * BN + row) * DIM + c16 * 8;
    ldsoff[j] = (j * 4 + wave) * 512;             // wave-uniform base
  }

#define STAGE(buf, k0)                                                        \
  do {                                                                        \
    _Pragma("unroll")                                                         \
    for (int j = 0; j < 4; ++j) gload16(&As[buf][ldsoff[j]], asrc[j] + (k0)); \
    _Pragma("unroll")                                                         \
    for (int j = 0; j < 4; ++j) gload16(&Bs[buf][ldsoff[j]], bsrc[j] + (k0)); \
  } while (0)

  const int wm = (wave >> 1) * 64;
  const int wn = (wave & 1) * 64;
  const int lr = lane & 15;
  const int hk = lane >> 4;        // k-group 0..3

  f32x4 acc[4][4];
#pragma unroll
  for (int m = 0; m < 4; ++m)
#pragma unroll
    for (int n = 0; n < 4; ++n) acc[m][n] = (f32x4)(0.0f);

  // prologue: two tiles in flight (16 outstanding loads/wave)
  STAGE(0, 0);
  STAGE(1, BK);

  int cur = 0;
  for (int kt = 0; kt < NT; ++kt) {
    // wait for OWN cur-tile loads (8 may remain = next tile's), then collective
    if (kt + 1 < NT) {
      asm volatile("s_waitcnt vmcnt(8)" ::: "memory");
    } else {
      asm volatile("s_waitcnt vmcnt(0)" ::: "memory");
    }
    __builtin_amdgcn_s_barrier();   // all waves' cur-tile loads landed

    bf16x8 fa[2][4], fb[2][4];
#pragma unroll
    for (int kk = 0; kk < 2; ++kk) {
#pragma unroll
      for (int m = 0; m < 4; ++m) {
        const int row = wm + m * 16 + lr;
        const int c16 = (kk * 4 + hk) ^ (row & 7);
        fa[kk][m] = *(const bf16x8*)&As[cur][row * 64 + c16 * 8];
      }
#pragma unroll
      for (int n = 0; n < 4; ++n) {
        const int row = wn + n * 16 + lr;
        const int c16 = (kk * 4 + hk) ^ (row & 7);
        fb[kk][n] = *(const bf16x8*)&Bs[cur][row * 64 + c16 * 8];
      }
    }

#pragma unroll
    for (int kk = 0; kk < 2; ++kk)
#pragma unroll
      for (int m = 0; m < 4; ++m)
#pragma unroll
        for (int n = 0; n < 4; ++n)
          acc[m][n] = __builtin_amdgcn_mfma_f32_16x16x32_bf16(
              fa[kk][m], fb[kk][n], acc[m][n], 0, 0, 0);

    __builtin_amdgcn_s_barrier();   // all waves done READING buf[cur]
    if (kt + 2 < NT) STAGE(cur, (kt + 2) * BK);  // refill cur (no drain)
    cur ^= 1;
  }
#undef STAGE

  // ---- epilogue: plain bf16 partial stores (deterministic, no atomics) ----
#pragma unroll
  for (int n = 0; n < 4; ++n) {
    const int hcol = cb * BN + wn + n * 16 + lr;
#pragma unroll
    for (int m = 0; m < 4; ++m) {
#pragma unroll
      for (int i = 0; i < 4; ++i) {
        int rloc = wm + m * 16 + hk * 4 + i;   // C/D: row=(lane>>4)*4+i
        int tr = tok[rloc];
        if (tr >= 0)
          pbf[((size_t)kslot[rloc] * NTOK + tr) * HID + hcol] =
              f2bf(acc[m][n][i]);
      }
    }
  }
}

// ---- combine: out[t] = 0.5*(p0 + p1 + b_e1 + b_e2); fully memory-bound -----
__global__ __launch_bounds__(256) void combine_kernel(
    const u16* __restrict__ pbf, const int* __restrict__ top2,
    const float* __restrict__ eb, float* __restrict__ out) {
  const int t = blockIdx.x;
  const int h = threadIdx.x * 8;
  const int m2 = top2[t];
  const int e1 = m2 & 15, e2 = (m2 >> 4) & 15;

  u16x8 p0 = *(const u16x8*)&pbf[(size_t)t * HID + h];
  u16x8 p1 = *(const u16x8*)&pbf[((size_t)NTOK + t) * HID + h];
  const float4* b1 = (const float4*)&eb[e1 * HID + h];
  const float4* b2 = (const float4*)&eb[e2 * HID + h];
  float4 b1a = b1[0], b1b = b1[1], b2a = b2[0], b2b = b2[1];

  float4 o0, o1;
  o0.x = 0.5f * (bf2f(p0[0]) + bf2f(p1[0]) + b1a.x + b2a.x);
  o0.y = 0.5f * (bf2f(p0[1]) + bf2f(p1[1]) + b1a.y + b2a.y);
  o0.z = 0.5f * (bf2f(p0[2]) + bf2f(p1[2]) + b1a.z + b2a.z);
  o0.w = 0.5f * (bf2f(p0[3]) + bf2f(p1[3]) + b1a.w + b2a.w);
  o1.x = 0.5f * (bf2f(p0[4]) + bf2f(p1[4]) + b1b.x + b2b.x);
  o1.y = 0.5f * (bf2f(p0[5]) + bf2f(p1[5]) + b1b.y + b2b.y);
  o1.z = 0.5f * (bf2f(p0[6]) + bf2f(p1[6]) + b1b.z + b2b.z);
  o1.w = 0.5f * (bf2f(p0[7]) + bf2f(p1[7]) + b1b.w + b2b.w);

  float4* po = (float4*)&out[(size_t)t * HID + h];
  po[0] = o0; po[1] = o1;
}

extern "C" void kernel_launch(void* const* d_in, const int* in_sizes, int n_in,
                              void* d_out, int out_size, void* d_ws, size_t ws_size,
                              hipStream_t stream) {
  const float* x  = (const float*)d_in[0];   // [4096,1024]
  const float* gW = (const float*)d_in[1];   // [8,1024]
  const float* gb = (const float*)d_in[2];   // [8]
  const float* eW = (const float*)d_in[3];   // [8,2048,1024]
  const float* eb = (const float*)d_in[4];   // [8,2048]

  float* out = (float*)d_out;
  float* var_out = out + (size_t)NTOK * HID;

  // ws layout
  char* ws = (char*)d_ws;
  int*   counts = (int*)ws;                                   // 32 B
  int*   lists  = (int*)(ws + 1024);                          // 128 KB
  float* probs  = (float*)(ws + 1024 + 131072);               // 128 KB
  int*   top2   = (int*)(ws + 1024 + 2 * 131072);             // 16 KB
  u16*   xbf    = (u16*)(ws + 294912);                        // 8 MB
  u16*   wbf    = (u16*)((char*)xbf + (size_t)NTOK * DIM * 2);// 32 MB
  u16*   pbf    = (u16*)((char*)wbf + (size_t)NEXP * HID * DIM * 2);  // 32 MB

  convert_bf16<<<(NEXP * HID * DIM) / (256 * 8), 256, 0, stream>>>(eW, wbf);
  gate_kernel<<<NTOK / 4, 256, 0, stream>>>(x, gW, gb, probs, top2, xbf);
  route_kernel<<<NEXP, 256, 0, stream>>>(probs, top2, counts, lists, var_out);
  expert_gemm<<<NEXP * (NTOK / BM) * (HID / BN), 256, 0, stream>>>(
      xbf, wbf, counts, lists, top2, pbf);
  combine_kernel<<<NTOK, 256, 0, stream>>>(pbf, top2, eb, out);
}

// Round 11
// 111.123 us; speedup vs baseline: 1.1950x; 1.0604x over previous
//
#include <hip/hip_runtime.h>

// SparseMoE: T=4096, D=1024, E=8, H=2048, top_k=2.
// R11: R8 base EXACTLY (128x128, BK=64 single-buffer 33KB LDS, swizzled
// global_load_lds, bf16 partial epilogue, no atomics) + ONE change:
// balanced XCD-chunked tile reorder. Logical L = cb*256 + e*32 + rb;
// XCD k = hw%8 owns L in [k*512,(k+1)*512) = 2 cb-columns x ALL experts x
// all rb -> B working set/XCD = 4MB = its L2, dead tiles identical across
// XCDs (fixes R9's expert-per-XCD imbalance).

#define NTOK 4096
#define DIM  1024
#define NEXP 8
#define HID  2048

#define BM 128
#define BN 128
#define BK 64

using u16    = unsigned short;
using u16x4  = __attribute__((ext_vector_type(4))) unsigned short;
using u16x8  = __attribute__((ext_vector_type(8))) unsigned short;
using bf16x8 = __attribute__((ext_vector_type(8))) __bf16;
using f32x4  = __attribute__((ext_vector_type(4))) float;

typedef const __attribute__((address_space(1))) unsigned char* gas1p;
typedef __attribute__((address_space(3))) unsigned char* gas3p;

__device__ __forceinline__ void gload16(void* lds, const void* g) {
  __builtin_amdgcn_global_load_lds((gas1p)g, (gas3p)lds, 16, 0, 0);
}

__device__ inline u16 f2bf(float f) {
  union { float f; unsigned u; } v; v.f = f;
  unsigned r = v.u + 0x7fffu + ((v.u >> 16) & 1u);  // RNE, no NaN in this data
  return (u16)(r >> 16);
}
__device__ inline float bf2f(u16 b) {
  union { unsigned u; float f; } v; v.u = ((unsigned)b) << 16; return v.f;
}

// ---------------- fp32 -> bf16 bulk convert (8 elems/thread) -----------------
__global__ __launch_bounds__(256) void convert_bf16(
    const float* __restrict__ in, u16* __restrict__ out) {
  int i = blockIdx.x * 256 + threadIdx.x;
  const float4* p = (const float4*)in + (size_t)i * 2;
  float4 a = p[0], b = p[1];
  u16x8 r;
  r[0] = f2bf(a.x); r[1] = f2bf(a.y); r[2] = f2bf(a.z); r[3] = f2bf(a.w);
  r[4] = f2bf(b.x); r[5] = f2bf(b.y); r[6] = f2bf(b.z); r[7] = f2bf(b.w);
  *((u16x8*)out + i) = r;
}

// -------- gating: fp64 logits, softmax, top-2 -> ws; also emits xbf ----------
__global__ __launch_bounds__(256) void gate_kernel(
    const float* __restrict__ x, const float* __restrict__ gW,
    const float* __restrict__ gb, float* __restrict__ probs,
    int* __restrict__ top2, u16* __restrict__ xbf) {
  const int wave = threadIdx.x >> 6;
  const int lane = threadIdx.x & 63;
  const int t = blockIdx.x * 4 + wave;

  const float4* xrow = (const float4*)(x + (size_t)t * DIM);
  double acc[NEXP];
#pragma unroll
  for (int e = 0; e < NEXP; ++e) acc[e] = 0.0;

#pragma unroll
  for (int c = 0; c < 4; ++c) {
    int idx = c * 64 + lane;          // float4 index; elems 4*idx..4*idx+3
    float4 xv = xrow[idx];
    u16x4 bv;
    bv[0] = f2bf(xv.x); bv[1] = f2bf(xv.y); bv[2] = f2bf(xv.z); bv[3] = f2bf(xv.w);
    *(u16x4*)(xbf + (size_t)t * DIM + 4 * idx) = bv;   // fused convert_x
#pragma unroll
    for (int e = 0; e < NEXP; ++e) {
      float4 wv = ((const float4*)(gW + (size_t)e * DIM))[idx];
      acc[e] += (double)xv.x * wv.x + (double)xv.y * wv.y +
                (double)xv.z * wv.z + (double)xv.w * wv.w;
    }
  }
#pragma unroll
  for (int e = 0; e < NEXP; ++e) {
    double v = acc[e];
#pragma unroll
    for (int off = 32; off > 0; off >>= 1) v += __shfl_down(v, off);
    acc[e] = v;
  }

  if (lane == 0) {
    double logits[NEXP];
#pragma unroll
    for (int e = 0; e < NEXP; ++e) logits[e] = acc[e] + (double)gb[e];
    double m = logits[0];
#pragma unroll
    for (int e = 1; e < NEXP; ++e) m = fmax(m, logits[e]);
    double p[NEXP], s = 0.0;
#pragma unroll
    for (int e = 0; e < NEXP; ++e) { p[e] = exp(logits[e] - m); s += p[e]; }
#pragma unroll
    for (int e = 0; e < NEXP; ++e) p[e] /= s;

    int i1 = 0;
#pragma unroll
    for (int e = 1; e < NEXP; ++e) if (p[e] > p[i1]) i1 = e;
    int i2 = (i1 == 0) ? 1 : 0;
#pragma unroll
    for (int e = 0; e < NEXP; ++e) {
      if (e != i1 && p[e] > p[i2]) i2 = e;
    }

#pragma unroll
    for (int e = 0; e < NEXP; ++e) probs[(size_t)t * NEXP + e] = (float)p[e];
    top2[t] = i1 | (i2 << 4);
  }
}

// ------- route: per-expert stable compaction (ballot prefix) + fp64 variance -
__global__ __launch_bounds__(256) void route_kernel(
    const float* __restrict__ probs, const int* __restrict__ top2,
    int* __restrict__ counts, int* __restrict__ lists,
    float* __restrict__ var_out) {
  const int e = blockIdx.x;
  const int tid = threadIdx.x;
  const int lane = tid & 63;
  const int wave = tid >> 6;

  __shared__ int wsum[4];
  __shared__ double ds[4], dq[4];

  double s = 0.0, q = 0.0;
  int base = 0;

  for (int c = 0; c < NTOK / 256; ++c) {
    int t = c * 256 + tid;
    float p = probs[(size_t)t * NEXP + e];
    s += (double)p;
    q += (double)p * (double)p;

    int m = top2[t];
    bool f = ((m & 15) == e) || (((m >> 4) & 15) == e);
    unsigned long long bal = __ballot(f);
    int before = __popcll(bal & ((1ull << lane) - 1ull));
    if (lane == 0) wsum[wave] = __popcll(bal);
    __syncthreads();
    int woff = 0;
#pragma unroll
    for (int w = 0; w < 4; ++w) if (w < wave) woff += wsum[w];
    int ctotal = wsum[0] + wsum[1] + wsum[2] + wsum[3];
    if (f) lists[e * NTOK + base + woff + before] = t;
    base += ctotal;
    __syncthreads();
  }
  if (tid == 0) counts[e] = base;

#pragma unroll
  for (int off = 32; off > 0; off >>= 1) {
    s += __shfl_down(s, off);
    q += __shfl_down(q, off);
  }
  if (lane == 0) { ds[wave] = s; dq[wave] = q; }
  __syncthreads();
  if (tid == 0) {
    double S = ds[0] + ds[1] + ds[2] + ds[3];
    double Q = dq[0] + dq[1] + dq[2] + dq[3];
    var_out[e] = (float)((Q - S * S / (double)NTOK) / (double)(NTOK - 1));
  }
}

// --------- gathered expert GEMM: R8 structure + balanced XCD chunking --------
// LDS tile (A and B): logical [128 rows][64 cols] bf16 row-major, 16B-chunk
// swizzle stored_c16 = c16 ^ (row&7). global_load_lds writes LDS linearly;
// global source carries the inverse (same) XOR. Epilogue: plain bf16 stores
// to partial[k][token][h], k = slot of expert e in token's top2.
__global__ __launch_bounds__(256, 2) void expert_gemm(
    const u16* __restrict__ xbf, const u16* __restrict__ wbf,
    const int* __restrict__ counts, const int* __restrict__ lists,
    const int* __restrict__ top2, u16* __restrict__ pbf) {
  __shared__ u16 As[BM * BK];   // 16 KB
  __shared__ u16 Bs[BN * BK];   // 16 KB
  __shared__ int tok[BM];
  __shared__ int kslot[BM];

  // Balanced XCD-chunked reorder: hw block i is dispatched to XCD i%8.
  // Logical L = cb*256 + e*32 + rb; XCD k owns L in [k*512,(k+1)*512)
  // = cb in {2k,2k+1} x all e x all rb. B working set/XCD = 16 panels
  // x 256KB = 4MB (fits per-XCD L2); dead-tile count identical per XCD.
  const int hw = blockIdx.x;
  const int L  = (hw & 7) * 512 + (hw >> 3);
  const int cb = L >> 8;
  const int e  = (L >> 5) & 7;
  const int rb = L & 31;
  const int cnt = counts[e];
  if (rb * BM >= cnt) return;

  const int tid  = threadIdx.x;
  const int wave = tid >> 6;
  const int lane = tid & 63;

  if (tid < BM) {
    int gi = rb * BM + tid;
    int tr = (gi < cnt) ? lists[e * NTOK + gi] : -1;
    tok[tid] = tr;
    kslot[tid] = (tr >= 0 && (top2[tr] & 15) == e) ? 0 : 1;
  }
  __syncthreads();

  // ---- staging precompute: 4 A-issues + 4 B-issues of 16B per thread ----
  const u16* asrc[4];
  const u16* bsrc[4];
  int ldsoff[4];
#pragma unroll
  for (int j = 0; j < 4; ++j) {
    const int idx  = (j * 4 + wave) * 64 + lane;  // 16B-chunk index in [0,1024)
    const int row  = idx >> 3;
    const int c16  = (idx & 7) ^ (row & 7);       // inverse swizzle on source
    int tr = tok[row]; if (tr < 0) tr = 0;        // clamped; row discarded later
    asrc[j] = xbf + (size_t)tr * DIM + c16 * 8;
    bsrc[j] = wbf + ((size_t)e * HID + (size_t)cb * BN + row) * DIM + c16 * 8;
    ldsoff[j] = (j * 4 + wave) * 512;             // wave-uniform base
  }

  const int wm = (wave >> 1) * 64;
  const int wn = (wave & 1) * 64;
  const int lr = lane & 15;
  const int hk = lane >> 4;        // k-group 0..3

  f32x4 acc[4][4];
#pragma unroll
  for (int m = 0; m < 4; ++m)
#pragma unroll
    for (int n = 0; n < 4; ++n) acc[m][n] = (f32x4)(0.0f);

  for (int k0 = 0; k0 < DIM; k0 += BK) {
#pragma unroll
    for (int j = 0; j < 4; ++j) gload16(&As[ldsoff[j]], asrc[j] + k0);
#pragma unroll
    for (int j = 0; j < 4; ++j) gload16(&Bs[ldsoff[j]], bsrc[j] + k0);

    __syncthreads();   // vmcnt(0) drain + barrier

    bf16x8 fa[2][4], fb[2][4];
#pragma unroll
    for (int kk = 0; kk < 2; ++kk) {
#pragma unroll
      for (int m = 0; m < 4; ++m) {
        const int row = wm + m * 16 + lr;
        const int c16 = (kk * 4 + hk) ^ (row & 7);
        fa[kk][m] = *(const bf16x8*)&As[row * 64 + c16 * 8];
      }
#pragma unroll
      for (int n = 0; n < 4; ++n) {
        const int row = wn + n * 16 + lr;
        const int c16 = (kk * 4 + hk) ^ (row & 7);
        fb[kk][n] = *(const bf16x8*)&Bs[row * 64 + c16 * 8];
      }
    }

#pragma unroll
    for (int kk = 0; kk < 2; ++kk)
#pragma unroll
      for (int m = 0; m < 4; ++m)
#pragma unroll
        for (int n = 0; n < 4; ++n)
          acc[m][n] = __builtin_amdgcn_mfma_f32_16x16x32_bf16(
              fa[kk][m], fb[kk][n], acc[m][n], 0, 0, 0);

    __syncthreads();
  }

  // ---- epilogue: plain bf16 partial stores (deterministic, no atomics) ----
#pragma unroll
  for (int n = 0; n < 4; ++n) {
    const int hcol = cb * BN + wn + n * 16 + lr;
#pragma unroll
    for (int m = 0; m < 4; ++m) {
#pragma unroll
      for (int i = 0; i < 4; ++i) {
        int rloc = wm + m * 16 + hk * 4 + i;   // C/D: row=(lane>>4)*4+i
        int tr = tok[rloc];
        if (tr >= 0)
          pbf[((size_t)kslot[rloc] * NTOK + tr) * HID + hcol] =
              f2bf(acc[m][n][i]);
      }
    }
  }
}

// ---- combine: out[t] = 0.5*(p0 + p1 + b_e1 + b_e2); fully memory-bound -----
__global__ __launch_bounds__(256) void combine_kernel(
    const u16* __restrict__ pbf, const int* __restrict__ top2,
    const float* __restrict__ eb, float* __restrict__ out) {
  const int t = blockIdx.x;
  const int h = threadIdx.x * 8;
  const int m2 = top2[t];
  const int e1 = m2 & 15, e2 = (m2 >> 4) & 15;

  u16x8 p0 = *(const u16x8*)&pbf[(size_t)t * HID + h];
  u16x8 p1 = *(const u16x8*)&pbf[((size_t)NTOK + t) * HID + h];
  const float4* b1 = (const float4*)&eb[e1 * HID + h];
  const float4* b2 = (const float4*)&eb[e2 * HID + h];
  float4 b1a = b1[0], b1b = b1[1], b2a = b2[0], b2b = b2[1];

  float4 o0, o1;
  o0.x = 0.5f * (bf2f(p0[0]) + bf2f(p1[0]) + b1a.x + b2a.x);
  o0.y = 0.5f * (bf2f(p0[1]) + bf2f(p1[1]) + b1a.y + b2a.y);
  o0.z = 0.5f * (bf2f(p0[2]) + bf2f(p1[2]) + b1a.z + b2a.z);
  o0.w = 0.5f * (bf2f(p0[3]) + bf2f(p1[3]) + b1a.w + b2a.w);
  o1.x = 0.5f * (bf2f(p0[4]) + bf2f(p1[4]) + b1b.x + b2b.x);
  o1.y = 0.5f * (bf2f(p0[5]) + bf2f(p1[5]) + b1b.y + b2b.y);
  o1.z = 0.5f * (bf2f(p0[6]) + bf2f(p1[6]) + b1b.z + b2b.z);
  o1.w = 0.5f * (bf2f(p0[7]) + bf2f(p1[7]) + b1b.w + b2b.w);

  float4* po = (float4*)&out[(size_t)t * HID + h];
  po[0] = o0; po[1] = o1;
}

extern "C" void kernel_launch(void* const* d_in, const int* in_sizes, int n_in,
                              void* d_out, int out_size, void* d_ws, size_t ws_size,
                              hipStream_t stream) {
  const float* x  = (const float*)d_in[0];   // [4096,1024]
  const float* gW = (const float*)d_in[1];   // [8,1024]
  const float* gb = (const float*)d_in[2];   // [8]
  const float* eW = (const float*)d_in[3];   // [8,2048,1024]
  const float* eb = (const float*)d_in[4];   // [8,2048]

  float* out = (float*)d_out;
  float* var_out = out + (size_t)NTOK * HID;

  // ws layout
  char* ws = (char*)d_ws;
  int*   counts = (int*)ws;                                   // 32 B
  int*   lists  = (int*)(ws + 1024);                          // 128 KB
  float* probs  = (float*)(ws + 1024 + 131072);               // 128 KB
  int*   top2   = (int*)(ws + 1024 + 2 * 131072);             // 16 KB
  u16*   xbf    = (u16*)(ws + 294912);                        // 8 MB
  u16*   wbf    = (u16*)((char*)xbf + (size_t)NTOK * DIM * 2);// 32 MB
  u16*   pbf    = (u16*)((char*)wbf + (size_t)NEXP * HID * DIM * 2);  // 32 MB

  convert_bf16<<<(NEXP * HID * DIM) / (256 * 8), 256, 0, stream>>>(eW, wbf);
  gate_kernel<<<NTOK / 4, 256, 0, stream>>>(x, gW, gb, probs, top2, xbf);
  route_kernel<<<NEXP, 256, 0, stream>>>(probs, top2, counts, lists, var_out);
  expert_gemm<<<NEXP * (NTOK / BM) * (HID / BN), 256, 0, stream>>>(
      xbf, wbf, counts, lists, top2, pbf);
  combine_kernel<<<NTOK, 256, 0, stream>>>(pbf, top2, eb, out);
}